// Round 3
// baseline (3948.901 us; speedup 1.0000x reference)
//
#include <hip/hip_runtime.h>

// ---------------------------------------------------------------------------
// Sparse 3D U-Net, round 3: fused out-stationary sparse conv.
//   inv[k][o] = input row for (offset k, out row o), -1 if absent (scatter).
//   Fused kernel: out-tile acc in LDS; per k: compact valid pairs, stage
//   gathered input rows, pair-lanes x col-groups FMA with LDS RMW into acc.
//   One coalesced store per out row. No global atomics, no contrib buffer.
// Workspace ~181 MB (round-1's 217 MB passed => safe).
// ---------------------------------------------------------------------------

#define CDIV(a, b) (((a) + (b)-1) / (b))

__global__ void fill_i32_k(int* __restrict__ buf, long n, int val) {
  long i = (long)blockIdx.x * blockDim.x + threadIdx.x;
  const long s = (long)gridDim.x * blockDim.x;
  for (; i < n; i += s) buf[i] = val;
}

// inv[k][om[k][p]] = im[k][p]  for valid pairs (om < n_out; pad == n_out).
__global__ void inv_build_k(const int* __restrict__ im, const int* __restrict__ om,
                            int P, const int* __restrict__ ndev, int nhost,
                            int* __restrict__ inv, int ldi) {
  const int n = (nhost >= 0) ? nhost : __ldg(ndev);
  const int k = blockIdx.y;
  const int p = blockIdx.x * 256 + threadIdx.x;
  if (p >= P) return;
  const int o = om[(long)k * P + p];
  if (o < n) inv[(long)k * ldi + o] = im[(long)k * P + p];
}

// Fused sparse conv: out[o] = sum_k fp[inv[k][o]] @ W[k]  (skip invalid).
// Input row = concat(fpA[in][0:CIN1], fpB[in][0:CIN2]).
template <int CIN1, int CIN2, int COUT, int TP, int SROWS>
__global__ __launch_bounds__(256) void sconv_fused_k(
    const float* __restrict__ fpA, const float* __restrict__ fpB,
    const float* __restrict__ W, const int* __restrict__ inv, int ldi,
    const int* __restrict__ ndev, int nhost, float* __restrict__ out) {
  constexpr int CIN = CIN1 + CIN2;
  constexpr int RN = 4;
  constexpr int NTX = COUT / RN;   // col-groups (4 cols each)
  constexpr int NPY = 256 / NTX;   // pair lanes
  constexpr int CP = CIN + 4;      // padded staging row (bank spread)
  constexpr int OP = COUT + 4;     // padded acc row (bank spread)
  constexpr int LV = CIN / 4, L1V = CIN1 / 4, CV = COUT / 4;
  static_assert(NTX * RN == COUT && NTX * NPY == 256, "geometry");
  static_assert(CIN1 % 4 == 0 && CIN2 % 4 == 0, "vec");

  const int n = (nhost >= 0) ? nhost : __ldg(ndev);
  const int o0 = blockIdx.x * TP;
  if (o0 >= n) return;
  const int rows = (n - o0 < TP) ? (n - o0) : TP;

  __shared__ float acc[TP][OP];
  __shared__ float ast[SROWS][CP];
  __shared__ int lr[TP];
  __shared__ int li[TP];
  __shared__ int mcnt;

  for (int i = threadIdx.x; i < TP * CV; i += 256) {
    const int r = i / CV, c = (i - r * CV) << 2;
    *reinterpret_cast<float4*>(&acc[r][c]) = make_float4(0.f, 0.f, 0.f, 0.f);
  }

  const int tx = threadIdx.x % NTX;
  const int py = threadIdx.x / NTX;

  for (int k = 0; k < 27; ++k) {
    __syncthreads();  // prev k's compute done; acc-zero done (k=0)
    if (threadIdx.x == 0) mcnt = 0;
    __syncthreads();
    if (threadIdx.x < rows) {
      const int iv = inv[(long)k * ldi + o0 + threadIdx.x];
      if (iv >= 0) {
        const int pos = atomicAdd(&mcnt, 1);
        lr[pos] = threadIdx.x;
        li[pos] = iv;
      }
    }
    __syncthreads();
    const int m = mcnt;
    if (m == 0) continue;
    const float* __restrict__ Wk = W + (long)k * (CIN * COUT);

    for (int s0 = 0; s0 < m; s0 += SROWS) {
      const int mb = (m - s0 < SROWS) ? (m - s0) : SROWS;
      // stage mb gathered input rows
      for (int i = threadIdx.x; i < mb * LV; i += 256) {
        const int s = i / LV, q = i - s * LV;
        const int in = li[s0 + s];
        float4 v;
        if (CIN2 == 0 || q < L1V)
          v = *reinterpret_cast<const float4*>(fpA + (long)in * CIN1 + (q << 2));
        else
          v = *reinterpret_cast<const float4*>(fpB + (long)in * CIN2 + ((q - L1V) << 2));
        *reinterpret_cast<float4*>(&ast[s][q << 2]) = v;
      }
      __syncthreads();
      // pair-lane x col-group FMA, LDS RMW into acc
      for (int s = py; s < mb; s += NPY) {
        const int r = lr[s0 + s];
        float4 a4 = *reinterpret_cast<const float4*>(&acc[r][tx * RN]);
        const float* __restrict__ as = &ast[s][0];
        const float* __restrict__ wp = Wk + tx * RN;
#pragma unroll 4
        for (int ci = 0; ci < CIN; ++ci) {
          const float av = as[ci];
          const float4 w4 = *reinterpret_cast<const float4*>(wp + (long)ci * COUT);
          a4.x = fmaf(av, w4.x, a4.x);
          a4.y = fmaf(av, w4.y, a4.y);
          a4.z = fmaf(av, w4.z, a4.z);
          a4.w = fmaf(av, w4.w, a4.w);
        }
        *reinterpret_cast<float4*>(&acc[r][tx * RN]) = a4;
      }
      __syncthreads();
    }
  }
  // epilogue: coalesced store of the tile
  for (int i = threadIdx.x; i < rows * CV; i += 256) {
    const int r = i / CV, c = (i - r * CV) << 2;
    *reinterpret_cast<float4*>(out + (long)(o0 + r) * COUT + c) =
        *reinterpret_cast<const float4*>(&acc[r][c]);
  }
}

// ---- BN (two-pass) ----
template <int C>
__global__ __launch_bounds__(256) void bn_stats_k(
    const float* __restrict__ x, const int* __restrict__ ndev, int nhost,
    float* __restrict__ sums) {
  constexpr int RPB = 256 / C;
  const int n = (nhost >= 0) ? nhost : __ldg(ndev);
  const int c = threadIdx.x % C;
  const int rsub = threadIdx.x / C;
  float s = 0.f, ss = 0.f;
  const long step = (long)gridDim.x * RPB;
  for (long r = (long)blockIdx.x * RPB + rsub; r < n; r += step) {
    const float v = x[r * C + c];
    s += v;
    ss = fmaf(v, v, ss);
  }
  __shared__ float sh[2][256];
  sh[0][threadIdx.x] = s;
  sh[1][threadIdx.x] = ss;
  __syncthreads();
  if (rsub == 0) {
#pragma unroll
    for (int j = 1; j < RPB; ++j) {
      s += sh[0][c + j * C];
      ss += sh[1][c + j * C];
    }
    atomicAdd(&sums[c], s);
    atomicAdd(&sums[C + c], ss);
  }
}

__global__ void bn_finalize_k(const float* __restrict__ sums,
                              const float* __restrict__ g, const float* __restrict__ b,
                              const int* __restrict__ ndev, int nhost, int C,
                              float* __restrict__ sb) {
  const int c = threadIdx.x;
  if (c >= C) return;
  const float n = (float)((nhost >= 0) ? nhost : __ldg(ndev));
  const float mean = sums[c] / n;
  const float var = sums[C + c] / n - mean * mean;
  const float sc = g[c] * rsqrtf(var + 1e-5f);
  sb[c] = sc;
  sb[C + c] = fmaf(-mean, sc, b[c]);
}

__global__ void bn_apply_k(float* __restrict__ x, int cols, int lc,
                           const float* __restrict__ sb,
                           const int* __restrict__ ndev, int nhost) {
  const int n = (nhost >= 0) ? nhost : __ldg(ndev);
  const long total = (long)n * cols;
  const long stride = (long)gridDim.x * blockDim.x;
  for (long i = (long)blockIdx.x * blockDim.x + threadIdx.x; i < total; i += stride) {
    const long r = i >> lc;
    const int c = (int)(i & (cols - 1));
    const float v = x[r * cols + c];
    x[r * cols + c] = fmaxf(fmaf(v, sb[c], sb[cols + c]), 0.f);
  }
}

// out[N0,20] = concat(t2[N0,32], e1[N0,32]) @ Wf[64,20]
__global__ __launch_bounds__(256) void final_gemm_k(
    const float* __restrict__ t2, const float* __restrict__ e1,
    const float* __restrict__ Wf, float* __restrict__ out, int n0) {
  __shared__ float w[64 * 20];
  for (int i = threadIdx.x; i < 64 * 20; i += 256) w[i] = Wf[i];
  __syncthreads();
  const int r = blockIdx.x * 256 + threadIdx.x;
  if (r >= n0) return;
  float acc[20];
#pragma unroll
  for (int c = 0; c < 20; ++c) acc[c] = 0.f;
#pragma unroll
  for (int j = 0; j < 32; j += 4) {
    const float4 v = *reinterpret_cast<const float4*>(t2 + (long)r * 32 + j);
    const float vv[4] = {v.x, v.y, v.z, v.w};
#pragma unroll
    for (int u = 0; u < 4; ++u)
#pragma unroll
      for (int c = 0; c < 20; ++c) acc[c] = fmaf(vv[u], w[(j + u) * 20 + c], acc[c]);
  }
#pragma unroll
  for (int j = 0; j < 32; j += 4) {
    const float4 v = *reinterpret_cast<const float4*>(e1 + (long)r * 32 + j);
    const float vv[4] = {v.x, v.y, v.z, v.w};
#pragma unroll
    for (int u = 0; u < 4; ++u)
#pragma unroll
      for (int c = 0; c < 20; ++c) acc[c] = fmaf(vv[u], w[(32 + j + u) * 20 + c], acc[c]);
  }
  float* __restrict__ orow = out + (long)r * 20;
#pragma unroll
  for (int c = 0; c < 20; ++c) orow[c] = acc[c];
}

// ---------------------------------------------------------------------------

extern "C" void kernel_launch(void* const* d_in, const int* in_sizes, int n_in,
                              void* d_out, int out_size, void* d_ws, size_t ws_size,
                              hipStream_t stream) {
  const float* feats = (const float*)d_in[0];
  const float* W1 = (const float*)d_in[1];
  const float* W2 = (const float*)d_in[2];
  const float* W3 = (const float*)d_in[3];
  const float* W4 = (const float*)d_in[4];
  const float* D4w = (const float*)d_in[5];
  const float* D3w = (const float*)d_in[6];
  const float* D2w = (const float*)d_in[7];
  const float* Wf = (const float*)d_in[8];
  const float* g1 = (const float*)d_in[9];   const float* b1 = (const float*)d_in[10];
  const float* g2 = (const float*)d_in[11];  const float* b2 = (const float*)d_in[12];
  const float* g3 = (const float*)d_in[13];  const float* b3 = (const float*)d_in[14];
  const float* g4 = (const float*)d_in[15];  const float* b4 = (const float*)d_in[16];
  const float* gd4 = (const float*)d_in[17]; const float* bd4 = (const float*)d_in[18];
  const float* gd3 = (const float*)d_in[19]; const float* bd3 = (const float*)d_in[20];
  const float* gd2 = (const float*)d_in[21]; const float* bd2 = (const float*)d_in[22];
  const int* m1i = (const int*)d_in[23]; const int* m1o = (const int*)d_in[24];
  const int* m2i = (const int*)d_in[25]; const int* m2o = (const int*)d_in[26];
  const int* m3i = (const int*)d_in[27]; const int* m3o = (const int*)d_in[28];
  const int* m4i = (const int*)d_in[29]; const int* m4o = (const int*)d_in[30];
  const int* n1d = (const int*)d_in[31];
  const int* n2d = (const int*)d_in[32];
  const int* n3d = (const int*)d_in[33];

  const int N0 = in_sizes[0] / 4;
  const int P1 = in_sizes[23] / 27;
  const int P2 = in_sizes[25] / 27;
  const int P3 = in_sizes[27] / 27;
  const int P4 = in_sizes[29] / 27;
  const int MAXN2 = (N0 < 65536) ? N0 : 65536;  // 2 * 32^3
  const int MAXN3 = (N0 < 8192) ? N0 : 8192;    // 2 * 16^3

  float* ws = (float*)d_ws;
  size_t off = 0;
  auto alloc = [&](size_t nf) {
    float* p = ws + off;
    off += (nf + 63) & ~(size_t)63;
    return p;
  };
  float* e1 = alloc((size_t)N0 * 32);
  float* e2 = alloc((size_t)N0 * 64);      // n1 rows used
  float* e3 = alloc((size_t)MAXN2 * 128);
  float* e4 = alloc((size_t)MAXN3 * 256);
  float* t4 = alloc((size_t)MAXN2 * 128);
  float* t3 = alloc((size_t)N0 * 64);      // n1 rows used
  float* t2 = alloc((size_t)N0 * 32);
  float* stats = alloc(7 * 1024);
  int* inv = (int*)alloc((size_t)27 * N0);
  if (off * sizeof(float) > ws_size) return;  // loud fail if scratch too small

  hipMemsetAsync(stats, 0, 7 * 1024 * sizeof(float), stream);
  const dim3 blk(256);
#define ST(i) (stats + (i)*1024)
#define SB(i) (stats + (i)*1024 + 512)

  // ---- conv1: 4->32, out rows N0 ----
  fill_i32_k<<<2048, blk, 0, stream>>>(inv, (long)27 * N0, -1);
  inv_build_k<<<dim3(CDIV(P1, 256), 27), blk, 0, stream>>>(m1i, m1o, P1, nullptr, N0, inv, N0);
  sconv_fused_k<4, 0, 32, 256, 64><<<CDIV(N0, 256), blk, 0, stream>>>(
      feats, nullptr, W1, inv, N0, nullptr, N0, e1);
  bn_stats_k<32><<<512, blk, 0, stream>>>(e1, nullptr, N0, ST(0));
  bn_finalize_k<<<1, blk, 0, stream>>>(ST(0), g1, b1, nullptr, N0, 32, SB(0));
  bn_apply_k<<<1024, blk, 0, stream>>>(e1, 32, 5, SB(0), nullptr, N0);

  // ---- conv2: 32->64, out rows n1 ----
  fill_i32_k<<<2048, blk, 0, stream>>>(inv, (long)27 * N0, -1);
  inv_build_k<<<dim3(CDIV(P2, 256), 27), blk, 0, stream>>>(m2i, m2o, P2, n1d, -1, inv, N0);
  sconv_fused_k<32, 0, 64, 128, 64><<<CDIV(N0, 128), blk, 0, stream>>>(
      e1, nullptr, W2, inv, N0, n1d, -1, e2);
  bn_stats_k<64><<<512, blk, 0, stream>>>(e2, n1d, -1, ST(1));
  bn_finalize_k<<<1, blk, 0, stream>>>(ST(1), g2, b2, n1d, -1, 64, SB(1));
  bn_apply_k<<<1024, blk, 0, stream>>>(e2, 64, 6, SB(1), n1d, -1);

  // ---- conv3: 64->128, out rows n2 ----
  fill_i32_k<<<2048, blk, 0, stream>>>(inv, (long)27 * MAXN2, -1);
  inv_build_k<<<dim3(CDIV(P3, 256), 27), blk, 0, stream>>>(m3i, m3o, P3, n2d, -1, inv, MAXN2);
  sconv_fused_k<64, 0, 128, 64, 64><<<CDIV(MAXN2, 64), blk, 0, stream>>>(
      e2, nullptr, W3, inv, MAXN2, n2d, -1, e3);
  bn_stats_k<128><<<512, blk, 0, stream>>>(e3, n2d, -1, ST(2));
  bn_finalize_k<<<1, blk, 0, stream>>>(ST(2), g3, b3, n2d, -1, 128, SB(2));
  bn_apply_k<<<1024, blk, 0, stream>>>(e3, 128, 7, SB(2), n2d, -1);

  // ---- conv4: 128->256, out rows n3 ----
  fill_i32_k<<<512, blk, 0, stream>>>(inv, (long)27 * MAXN3, -1);
  inv_build_k<<<dim3(CDIV(P4, 256), 27), blk, 0, stream>>>(m4i, m4o, P4, n3d, -1, inv, MAXN3);
  sconv_fused_k<128, 0, 256, 32, 32><<<CDIV(MAXN3, 32), blk, 0, stream>>>(
      e3, nullptr, W4, inv, MAXN3, n3d, -1, e4);
  bn_stats_k<256><<<512, blk, 0, stream>>>(e4, n3d, -1, ST(3));
  bn_finalize_k<<<1, blk, 0, stream>>>(ST(3), g4, b4, n3d, -1, 256, SB(3));
  bn_apply_k<<<512, blk, 0, stream>>>(e4, 256, 8, SB(3), n3d, -1);

  // ---- D4: tconv 256->128 (maps swapped), out rows n2 ----
  fill_i32_k<<<2048, blk, 0, stream>>>(inv, (long)27 * MAXN2, -1);
  inv_build_k<<<dim3(CDIV(P4, 256), 27), blk, 0, stream>>>(m4o, m4i, P4, n2d, -1, inv, MAXN2);
  sconv_fused_k<256, 0, 128, 32, 32><<<CDIV(MAXN2, 32), blk, 0, stream>>>(
      e4, nullptr, D4w, inv, MAXN2, n2d, -1, t4);
  bn_stats_k<128><<<512, blk, 0, stream>>>(t4, n2d, -1, ST(4));
  bn_finalize_k<<<1, blk, 0, stream>>>(ST(4), gd4, bd4, n2d, -1, 128, SB(4));
  bn_apply_k<<<1024, blk, 0, stream>>>(t4, 128, 7, SB(4), n2d, -1);

  // ---- D3: tconv 256->64, input concat(t4, e3), out rows n1 ----
  fill_i32_k<<<2048, blk, 0, stream>>>(inv, (long)27 * N0, -1);
  inv_build_k<<<dim3(CDIV(P3, 256), 27), blk, 0, stream>>>(m3o, m3i, P3, n1d, -1, inv, N0);
  sconv_fused_k<128, 128, 64, 64, 32><<<CDIV(N0, 64), blk, 0, stream>>>(
      t4, e3, D3w, inv, N0, n1d, -1, t3);
  bn_stats_k<64><<<512, blk, 0, stream>>>(t3, n1d, -1, ST(5));
  bn_finalize_k<<<1, blk, 0, stream>>>(ST(5), gd3, bd3, n1d, -1, 64, SB(5));
  bn_apply_k<<<1024, blk, 0, stream>>>(t3, 64, 6, SB(5), n1d, -1);

  // ---- D2: tconv 128->32, input concat(t3, e2), out rows N0 ----
  fill_i32_k<<<2048, blk, 0, stream>>>(inv, (long)27 * N0, -1);
  inv_build_k<<<dim3(CDIV(P2, 256), 27), blk, 0, stream>>>(m2o, m2i, P2, nullptr, N0, inv, N0);
  sconv_fused_k<64, 64, 32, 256, 32><<<CDIV(N0, 256), blk, 0, stream>>>(
      t3, e2, D2w, inv, N0, nullptr, N0, t2);
  bn_stats_k<32><<<512, blk, 0, stream>>>(t2, nullptr, N0, ST(6));
  bn_finalize_k<<<1, blk, 0, stream>>>(ST(6), gd2, bd2, nullptr, N0, 32, SB(6));
  bn_apply_k<<<1024, blk, 0, stream>>>(t2, 32, 5, SB(6), nullptr, N0);

  // ---- final 1x1: out = concat(t2, e1) @ Wf ----
  final_gemm_k<<<CDIV(N0, 256), blk, 0, stream>>>(t2, e1, Wf, (float*)d_out, N0);

#undef ST
#undef SB
}